// Round 1
// baseline (773.469 us; speedup 1.0000x reference)
//
#include <hip/hip_runtime.h>

#define N_NODES 50000
#define N_EDGES 800000
#define IN_DIM 16
#define OUT_DIM 16
#define N_RELS 90
#define N_BASES 30

// ---------------------------------------------------------------------------
// Prep: W_rel (basis recombination with the reference's exact reshape
// semantics) + folded attention vectors a1,a2,a3 (Ws^T @ Wa chunks).
// W_rel_flat[f] with f = a*1440 + r*16 + o  (a = "in" index after the
// [30,16,16]->[16,30,16] reshape), stored so that the edge kernel reads
// W_rel[rel*256 + i*16 + o].
// ---------------------------------------------------------------------------
__global__ __launch_bounds__(256) void prep_kernel(
    const float* __restrict__ Ws,      // [16,16]  (out,in)
    const float* __restrict__ Wa,      // [1,48]
    const float* __restrict__ weight,  // [30,16,16] flat
    const float* __restrict__ w_comp,  // [90,30]
    float* __restrict__ Wrel,          // [90*256]
    float* __restrict__ avec)          // [48]
{
    int f = blockIdx.x * blockDim.x + threadIdx.x;
    if (f < N_RELS * IN_DIM * OUT_DIM) {
        // tmp[a, r, o] = sum_b w_comp[r,b] * V[a,b,o],  V[a,b,o] = weight_flat[a*480 + b*16 + o]
        int a   = f / (N_RELS * OUT_DIM);
        int rem = f % (N_RELS * OUT_DIM);
        int r   = rem / OUT_DIM;
        int o   = rem % OUT_DIM;
        float acc = 0.f;
        #pragma unroll
        for (int b = 0; b < N_BASES; ++b)
            acc += w_comp[r * N_BASES + b] * weight[a * (N_BASES * OUT_DIM) + b * OUT_DIM + o];
        Wrel[f] = acc;
    } else if (f < N_RELS * IN_DIM * OUT_DIM + 48) {
        int g = f - N_RELS * IN_DIM * OUT_DIM;
        int k = g / IN_DIM;   // which third of Wa
        int i = g % IN_DIM;   // input index
        float acc = 0.f;
        #pragma unroll
        for (int o = 0; o < OUT_DIM; ++o)
            acc += Wa[k * OUT_DIM + o] * Ws[o * IN_DIM + i];
        avec[g] = acc;
    }
}

// ---------------------------------------------------------------------------
// Edge kernel: one thread per edge.
//   score = h[src]·a1 + he[e]·a2 + h[dst]·a3
//   msg[o] = (sum_i h[src][i] * Wrel[rel][i][o]) * score
//   atomicAdd into h_out[dst]
// ---------------------------------------------------------------------------
__global__ __launch_bounds__(256) void edge_kernel(
    const float* __restrict__ h,
    const float* __restrict__ he,
    const int* __restrict__ src,
    const int* __restrict__ dst,
    const int* __restrict__ rel,
    const float* __restrict__ Wrel,
    const float* __restrict__ avec,
    float* __restrict__ hout)
{
    int e = blockIdx.x * blockDim.x + threadIdx.x;
    if (e >= N_EDGES) return;

    int s = src[e];
    int d = dst[e];
    int r = rel[e];

    // h[src] into registers (4x float4, coalesced-ish gather of 64B rows)
    float hs[IN_DIM];
    {
        const float4* p = (const float4*)(h + (size_t)s * IN_DIM);
        #pragma unroll
        for (int i = 0; i < 4; ++i) {
            float4 v = p[i];
            hs[4*i+0] = v.x; hs[4*i+1] = v.y; hs[4*i+2] = v.z; hs[4*i+3] = v.w;
        }
    }

    // score
    float score = 0.f;
    #pragma unroll
    for (int i = 0; i < IN_DIM; ++i) score += hs[i] * avec[i];
    {
        const float4* p = (const float4*)(he + (size_t)e * IN_DIM);
        #pragma unroll
        for (int i = 0; i < 4; ++i) {
            float4 v = p[i];
            score += v.x * avec[16 + 4*i + 0] + v.y * avec[16 + 4*i + 1]
                   + v.z * avec[16 + 4*i + 2] + v.w * avec[16 + 4*i + 3];
        }
    }
    {
        const float4* p = (const float4*)(h + (size_t)d * IN_DIM);
        #pragma unroll
        for (int i = 0; i < 4; ++i) {
            float4 v = p[i];
            score += v.x * avec[32 + 4*i + 0] + v.y * avec[32 + 4*i + 1]
                   + v.z * avec[32 + 4*i + 2] + v.w * avec[32 + 4*i + 3];
        }
    }

    // msg = h_src @ Wrel[rel]  (16x16), accumulated in 4x float4
    float4 acc0 = {0,0,0,0}, acc1 = {0,0,0,0}, acc2 = {0,0,0,0}, acc3 = {0,0,0,0};
    const float4* W = (const float4*)(Wrel + (size_t)r * (IN_DIM * OUT_DIM));
    #pragma unroll
    for (int i = 0; i < IN_DIM; ++i) {
        float hv = hs[i];
        float4 w0 = W[i*4+0], w1 = W[i*4+1], w2 = W[i*4+2], w3 = W[i*4+3];
        acc0.x += hv * w0.x; acc0.y += hv * w0.y; acc0.z += hv * w0.z; acc0.w += hv * w0.w;
        acc1.x += hv * w1.x; acc1.y += hv * w1.y; acc1.z += hv * w1.z; acc1.w += hv * w1.w;
        acc2.x += hv * w2.x; acc2.y += hv * w2.y; acc2.z += hv * w2.z; acc2.w += hv * w2.w;
        acc3.x += hv * w3.x; acc3.y += hv * w3.y; acc3.z += hv * w3.z; acc3.w += hv * w3.w;
    }

    float* outp = hout + (size_t)d * OUT_DIM;
    atomicAdd(outp + 0,  acc0.x * score);
    atomicAdd(outp + 1,  acc0.y * score);
    atomicAdd(outp + 2,  acc0.z * score);
    atomicAdd(outp + 3,  acc0.w * score);
    atomicAdd(outp + 4,  acc1.x * score);
    atomicAdd(outp + 5,  acc1.y * score);
    atomicAdd(outp + 6,  acc1.z * score);
    atomicAdd(outp + 7,  acc1.w * score);
    atomicAdd(outp + 8,  acc2.x * score);
    atomicAdd(outp + 9,  acc2.y * score);
    atomicAdd(outp + 10, acc2.z * score);
    atomicAdd(outp + 11, acc2.w * score);
    atomicAdd(outp + 12, acc3.x * score);
    atomicAdd(outp + 13, acc3.y * score);
    atomicAdd(outp + 14, acc3.z * score);
    atomicAdd(outp + 15, acc3.w * score);
}

extern "C" void kernel_launch(void* const* d_in, const int* in_sizes, int n_in,
                              void* d_out, int out_size, void* d_ws, size_t ws_size,
                              hipStream_t stream) {
    const float* h      = (const float*)d_in[0];  // [N,16]
    const float* he     = (const float*)d_in[1];  // [E,16]
    const float* Ws     = (const float*)d_in[2];  // [16,16]
    const float* Wa     = (const float*)d_in[3];  // [1,48]
    const float* weight = (const float*)d_in[4];  // [30,16,16]
    const float* w_comp = (const float*)d_in[5];  // [90,30]
    const int*   src    = (const int*)d_in[6];    // [E]
    const int*   dst    = (const int*)d_in[7];    // [E]
    const int*   rel    = (const int*)d_in[8];    // [E]
    float* hout = (float*)d_out;                  // [N,16]

    float* Wrel = (float*)d_ws;                   // 23040 floats
    float* avec = Wrel + N_RELS * IN_DIM * OUT_DIM; // 48 floats

    // d_out is poisoned before every launch: zero it (scatter-sum target).
    hipMemsetAsync(d_out, 0, (size_t)out_size * sizeof(float), stream);

    {
        int total = N_RELS * IN_DIM * OUT_DIM + 48;
        int blocks = (total + 255) / 256;
        prep_kernel<<<blocks, 256, 0, stream>>>(Ws, Wa, weight, w_comp, Wrel, avec);
    }
    {
        int blocks = (N_EDGES + 255) / 256;
        edge_kernel<<<blocks, 256, 0, stream>>>(h, he, src, dst, rel, Wrel, avec, hout);
    }
}

// Round 2
// 421.865 us; speedup vs baseline: 1.8335x; 1.8335x over previous
//
#include <hip/hip_runtime.h>

#define N_NODES 50000
#define N_EDGES 800000
#define IN_DIM 16
#define OUT_DIM 16
#define N_RELS 90
#define N_BASES 30

#define SCAN_THREADS 1024
#define SCAN_CHUNK 49  // 1024*49 = 50176 >= 50000

// ---------------------------------------------------------------------------
// Prep: W_rel (basis recombination, reference reshape semantics) + folded
// attention vectors a1,a2,a3 (Ws^T @ Wa chunks).
// ---------------------------------------------------------------------------
__global__ __launch_bounds__(256) void prep_kernel(
    const float* __restrict__ Ws,      // [16,16]  (out,in)
    const float* __restrict__ Wa,      // [1,48]
    const float* __restrict__ weight,  // [30,16,16] flat
    const float* __restrict__ w_comp,  // [90,30]
    float* __restrict__ Wrel,          // [90*256]
    float* __restrict__ avec)          // [48]
{
    int f = blockIdx.x * blockDim.x + threadIdx.x;
    if (f < N_RELS * IN_DIM * OUT_DIM) {
        int a   = f / (N_RELS * OUT_DIM);
        int rem = f % (N_RELS * OUT_DIM);
        int r   = rem / OUT_DIM;
        int o   = rem % OUT_DIM;
        float acc = 0.f;
        #pragma unroll
        for (int b = 0; b < N_BASES; ++b)
            acc += w_comp[r * N_BASES + b] * weight[a * (N_BASES * OUT_DIM) + b * OUT_DIM + o];
        Wrel[f] = acc;
    } else if (f < N_RELS * IN_DIM * OUT_DIM + 48) {
        int g = f - N_RELS * IN_DIM * OUT_DIM;
        int k = g / IN_DIM;
        int i = g % IN_DIM;
        float acc = 0.f;
        #pragma unroll
        for (int o = 0; o < OUT_DIM; ++o)
            acc += Wa[k * OUT_DIM + o] * Ws[o * IN_DIM + i];
        avec[g] = acc;
    }
}

// ---------------------------------------------------------------------------
// Phase 1: histogram of destinations.
// ---------------------------------------------------------------------------
__global__ __launch_bounds__(256) void count_kernel(
    const int* __restrict__ dst, int* __restrict__ cnt)
{
    int e = blockIdx.x * blockDim.x + threadIdx.x;
    if (e < N_EDGES) atomicAdd(&cnt[dst[e]], 1);
}

// ---------------------------------------------------------------------------
// Phase 2: single-block exclusive scan of cnt[50000] -> base, cursor.
// base[N_NODES] = N_EDGES.
// ---------------------------------------------------------------------------
__global__ __launch_bounds__(SCAN_THREADS) void scan_kernel(
    const int* __restrict__ cnt,
    int* __restrict__ base,    // [N_NODES+1]
    int* __restrict__ cursor)  // [N_NODES]
{
    __shared__ int s[SCAN_THREADS];
    int t = threadIdx.x;

    int partial = 0;
    #pragma unroll 4
    for (int i = 0; i < SCAN_CHUNK; ++i) {
        int idx = t * SCAN_CHUNK + i;
        if (idx < N_NODES) partial += cnt[idx];
    }
    s[t] = partial;
    __syncthreads();

    // Hillis-Steele inclusive scan over 1024 partials
    #pragma unroll
    for (int d = 1; d < SCAN_THREADS; d <<= 1) {
        int v = (t >= d) ? s[t - d] : 0;
        __syncthreads();
        s[t] += v;
        __syncthreads();
    }
    int running = s[t] - partial;  // exclusive prefix for this thread's chunk

    for (int i = 0; i < SCAN_CHUNK; ++i) {
        int idx = t * SCAN_CHUNK + i;
        if (idx < N_NODES) {
            base[idx] = running;
            cursor[idx] = running;
            running += cnt[idx];
        }
    }
    if (t == 0) base[N_NODES] = N_EDGES;
}

// ---------------------------------------------------------------------------
// Phase 3: per-edge message compute, stored at its CSR slot (no out atomics).
// ---------------------------------------------------------------------------
__global__ __launch_bounds__(256) void compute_kernel(
    const float* __restrict__ h,
    const float* __restrict__ he,
    const int* __restrict__ src,
    const int* __restrict__ dst,
    const int* __restrict__ rel,
    const float* __restrict__ Wrel,
    const float* __restrict__ avec,
    int* __restrict__ cursor,
    float* __restrict__ msg)   // [N_EDGES*16], permuted by dst-segment
{
    int e = blockIdx.x * blockDim.x + threadIdx.x;
    if (e >= N_EDGES) return;

    int s = src[e];
    int d = dst[e];
    int r = rel[e];

    int pos = atomicAdd(&cursor[d], 1);  // claim slot in d's segment

    float hs[IN_DIM];
    {
        const float4* p = (const float4*)(h + (size_t)s * IN_DIM);
        #pragma unroll
        for (int i = 0; i < 4; ++i) {
            float4 v = p[i];
            hs[4*i+0] = v.x; hs[4*i+1] = v.y; hs[4*i+2] = v.z; hs[4*i+3] = v.w;
        }
    }

    float score = 0.f;
    #pragma unroll
    for (int i = 0; i < IN_DIM; ++i) score += hs[i] * avec[i];
    {
        const float4* p = (const float4*)(he + (size_t)e * IN_DIM);
        #pragma unroll
        for (int i = 0; i < 4; ++i) {
            float4 v = p[i];
            score += v.x * avec[16 + 4*i + 0] + v.y * avec[16 + 4*i + 1]
                   + v.z * avec[16 + 4*i + 2] + v.w * avec[16 + 4*i + 3];
        }
    }
    {
        const float4* p = (const float4*)(h + (size_t)d * IN_DIM);
        #pragma unroll
        for (int i = 0; i < 4; ++i) {
            float4 v = p[i];
            score += v.x * avec[32 + 4*i + 0] + v.y * avec[32 + 4*i + 1]
                   + v.z * avec[32 + 4*i + 2] + v.w * avec[32 + 4*i + 3];
        }
    }

    float4 acc0 = {0,0,0,0}, acc1 = {0,0,0,0}, acc2 = {0,0,0,0}, acc3 = {0,0,0,0};
    const float4* W = (const float4*)(Wrel + (size_t)r * (IN_DIM * OUT_DIM));
    #pragma unroll
    for (int i = 0; i < IN_DIM; ++i) {
        float hv = hs[i];
        float4 w0 = W[i*4+0], w1 = W[i*4+1], w2 = W[i*4+2], w3 = W[i*4+3];
        acc0.x += hv * w0.x; acc0.y += hv * w0.y; acc0.z += hv * w0.z; acc0.w += hv * w0.w;
        acc1.x += hv * w1.x; acc1.y += hv * w1.y; acc1.z += hv * w1.z; acc1.w += hv * w1.w;
        acc2.x += hv * w2.x; acc2.y += hv * w2.y; acc2.z += hv * w2.z; acc2.w += hv * w2.w;
        acc3.x += hv * w3.x; acc3.y += hv * w3.y; acc3.z += hv * w3.z; acc3.w += hv * w3.w;
    }

    float4* out = (float4*)(msg + (size_t)pos * OUT_DIM);
    acc0.x *= score; acc0.y *= score; acc0.z *= score; acc0.w *= score;
    acc1.x *= score; acc1.y *= score; acc1.z *= score; acc1.w *= score;
    acc2.x *= score; acc2.y *= score; acc2.z *= score; acc2.w *= score;
    acc3.x *= score; acc3.y *= score; acc3.z *= score; acc3.w *= score;
    out[0] = acc0; out[1] = acc1; out[2] = acc2; out[3] = acc3;
}

// ---------------------------------------------------------------------------
// Phase 4: segmented reduce. 16 threads per node (o-columns), coalesced 64B
// row reads, single coalesced write of h_out. No atomics.
// ---------------------------------------------------------------------------
__global__ __launch_bounds__(256) void reduce_kernel(
    const float* __restrict__ msg,
    const int* __restrict__ base,
    float* __restrict__ hout)
{
    int tid = blockIdx.x * blockDim.x + threadIdx.x;
    int n = tid / OUT_DIM;
    int o = tid % OUT_DIM;
    if (n >= N_NODES) return;

    int beg = base[n];
    int end = base[n + 1];
    float acc = 0.f;
    for (int j = beg; j < end; ++j)
        acc += msg[(size_t)j * OUT_DIM + o];
    hout[(size_t)n * OUT_DIM + o] = acc;
}

// ---------------------------------------------------------------------------
// Fallback (ws too small): R1-style direct atomic scatter.
// ---------------------------------------------------------------------------
__global__ __launch_bounds__(256) void edge_atomic_kernel(
    const float* __restrict__ h,
    const float* __restrict__ he,
    const int* __restrict__ src,
    const int* __restrict__ dst,
    const int* __restrict__ rel,
    const float* __restrict__ Wrel,
    const float* __restrict__ avec,
    float* __restrict__ hout)
{
    int e = blockIdx.x * blockDim.x + threadIdx.x;
    if (e >= N_EDGES) return;
    int s = src[e], d = dst[e], r = rel[e];
    float hs[IN_DIM];
    const float4* p = (const float4*)(h + (size_t)s * IN_DIM);
    #pragma unroll
    for (int i = 0; i < 4; ++i) {
        float4 v = p[i];
        hs[4*i+0] = v.x; hs[4*i+1] = v.y; hs[4*i+2] = v.z; hs[4*i+3] = v.w;
    }
    float score = 0.f;
    #pragma unroll
    for (int i = 0; i < IN_DIM; ++i) score += hs[i] * avec[i];
    const float4* q = (const float4*)(he + (size_t)e * IN_DIM);
    #pragma unroll
    for (int i = 0; i < 4; ++i) {
        float4 v = q[i];
        score += v.x * avec[16+4*i] + v.y * avec[17+4*i] + v.z * avec[18+4*i] + v.w * avec[19+4*i];
    }
    const float4* pd = (const float4*)(h + (size_t)d * IN_DIM);
    #pragma unroll
    for (int i = 0; i < 4; ++i) {
        float4 v = pd[i];
        score += v.x * avec[32+4*i] + v.y * avec[33+4*i] + v.z * avec[34+4*i] + v.w * avec[35+4*i];
    }
    float acc[OUT_DIM];
    #pragma unroll
    for (int o = 0; o < OUT_DIM; ++o) acc[o] = 0.f;
    const float* W = Wrel + (size_t)r * (IN_DIM * OUT_DIM);
    #pragma unroll
    for (int i = 0; i < IN_DIM; ++i) {
        float hv = hs[i];
        #pragma unroll
        for (int o = 0; o < OUT_DIM; ++o) acc[o] += hv * W[i * OUT_DIM + o];
    }
    float* outp = hout + (size_t)d * OUT_DIM;
    #pragma unroll
    for (int o = 0; o < OUT_DIM; ++o) atomicAdd(outp + o, acc[o] * score);
}

extern "C" void kernel_launch(void* const* d_in, const int* in_sizes, int n_in,
                              void* d_out, int out_size, void* d_ws, size_t ws_size,
                              hipStream_t stream) {
    const float* h      = (const float*)d_in[0];
    const float* he     = (const float*)d_in[1];
    const float* Ws     = (const float*)d_in[2];
    const float* Wa     = (const float*)d_in[3];
    const float* weight = (const float*)d_in[4];
    const float* w_comp = (const float*)d_in[5];
    const int*   src    = (const int*)d_in[6];
    const int*   dst    = (const int*)d_in[7];
    const int*   rel    = (const int*)d_in[8];
    float* hout = (float*)d_out;

    // ws layout (float offsets)
    const size_t OFF_WREL   = 0;                       // 23040 f
    const size_t OFF_AVEC   = 23040;                   // 48 f
    const size_t OFF_CNT    = 23104;                   // 50000 i
    const size_t OFF_BASE   = 73104;                   // 50001 i
    const size_t OFF_CURSOR = 123112;                  // 50000 i
    const size_t OFF_MSG    = 173120;                  // 12,800,000 f (64B aligned)
    const size_t NEED_BYTES = (OFF_MSG + (size_t)N_EDGES * OUT_DIM) * 4;

    float* wsf = (float*)d_ws;
    float* Wrel = wsf + OFF_WREL;
    float* avec = wsf + OFF_AVEC;

    {
        int total = N_RELS * IN_DIM * OUT_DIM + 48;
        prep_kernel<<<(total + 255) / 256, 256, 0, stream>>>(Ws, Wa, weight, w_comp, Wrel, avec);
    }

    if (ws_size >= NEED_BYTES) {
        int* cnt    = (int*)(wsf + OFF_CNT);
        int* csbase = (int*)(wsf + OFF_BASE);
        int* cursor = (int*)(wsf + OFF_CURSOR);
        float* msg  = wsf + OFF_MSG;

        hipMemsetAsync(cnt, 0, N_NODES * sizeof(int), stream);
        count_kernel<<<(N_EDGES + 255) / 256, 256, 0, stream>>>(dst, cnt);
        scan_kernel<<<1, SCAN_THREADS, 0, stream>>>(cnt, csbase, cursor);
        compute_kernel<<<(N_EDGES + 255) / 256, 256, 0, stream>>>(
            h, he, src, dst, rel, Wrel, avec, cursor, msg);
        reduce_kernel<<<(N_NODES * OUT_DIM + 255) / 256, 256, 0, stream>>>(msg, csbase, hout);
    } else {
        hipMemsetAsync(d_out, 0, (size_t)out_size * sizeof(float), stream);
        edge_atomic_kernel<<<(N_EDGES + 255) / 256, 256, 0, stream>>>(
            h, he, src, dst, rel, Wrel, avec, hout);
    }
}

// Round 3
// 367.575 us; speedup vs baseline: 2.1042x; 1.1477x over previous
//
#include <hip/hip_runtime.h>

#define N_NODES 50000
#define N_EDGES 800000
#define IN_DIM 16
#define OUT_DIM 16
#define N_RELS 90
#define N_BASES 30

// ---------------------------------------------------------------------------
// Prep: W_rel (basis recombination, reference reshape semantics) + folded
// attention vectors a1,a2,a3 (Ws^T @ Wa chunks).
// ---------------------------------------------------------------------------
__global__ __launch_bounds__(256) void prep_kernel(
    const float* __restrict__ Ws,      // [16,16]  (out,in)
    const float* __restrict__ Wa,      // [1,48]
    const float* __restrict__ weight,  // [30,16,16] flat
    const float* __restrict__ w_comp,  // [90,30]
    float* __restrict__ Wrel,          // [90*256]
    float* __restrict__ avec)          // [48]
{
    int f = blockIdx.x * blockDim.x + threadIdx.x;
    if (f < N_RELS * IN_DIM * OUT_DIM) {
        int a   = f / (N_RELS * OUT_DIM);
        int rem = f % (N_RELS * OUT_DIM);
        int r   = rem / OUT_DIM;
        int o   = rem % OUT_DIM;
        float acc = 0.f;
        #pragma unroll
        for (int b = 0; b < N_BASES; ++b)
            acc += w_comp[r * N_BASES + b] * weight[a * (N_BASES * OUT_DIM) + b * OUT_DIM + o];
        Wrel[f] = acc;
    } else if (f < N_RELS * IN_DIM * OUT_DIM + 48) {
        int g = f - N_RELS * IN_DIM * OUT_DIM;
        int k = g / IN_DIM;
        int i = g % IN_DIM;
        float acc = 0.f;
        #pragma unroll
        for (int o = 0; o < OUT_DIM; ++o)
            acc += Wa[k * OUT_DIM + o] * Ws[o * IN_DIM + i];
        avec[g] = acc;
    }
}

// ---------------------------------------------------------------------------
// Per-node score dots: s13[n] = { h[n]·a1 , h[n]·a3 }. Same accumulation
// order as the original per-edge dot -> identical rounding. Warms L2 with h.
// ---------------------------------------------------------------------------
__global__ __launch_bounds__(256) void node_dots_kernel(
    const float* __restrict__ h,
    const float* __restrict__ avec,
    float2* __restrict__ s13)
{
    int n = blockIdx.x * blockDim.x + threadIdx.x;
    if (n >= N_NODES) return;
    const float4* p = (const float4*)(h + (size_t)n * IN_DIM);
    float d1 = 0.f, d3 = 0.f;
    #pragma unroll
    for (int i = 0; i < 4; ++i) {
        float4 v = p[i];
        d1 += v.x * avec[4*i+0] + v.y * avec[4*i+1] + v.z * avec[4*i+2] + v.w * avec[4*i+3];
        d3 += v.x * avec[32+4*i+0] + v.y * avec[32+4*i+1] + v.z * avec[32+4*i+2] + v.w * avec[32+4*i+3];
    }
    s13[n] = make_float2(d1, d3);
}

// ---------------------------------------------------------------------------
// Edge compute: 2-edge batch per thread iteration for MLP. Coalesced msg/next
// stores; one atomicExch per edge builds per-dst linked lists.
// ---------------------------------------------------------------------------
#define EDGES_PER_BLOCK 512

__global__ __launch_bounds__(256, 2) void compute_kernel(
    const float* __restrict__ h,
    const float* __restrict__ he,
    const int* __restrict__ src,
    const int* __restrict__ dst,
    const int* __restrict__ rel,
    const float* __restrict__ Wrel,
    const float* __restrict__ avec,
    const float2* __restrict__ s13,
    int* __restrict__ head,    // [N_NODES], init -1
    int* __restrict__ next,    // [N_EDGES]
    float* __restrict__ msg)   // [N_EDGES*16], indexed by e (coalesced)
{
    const int t = threadIdx.x;
    const int e0 = blockIdx.x * EDGES_PER_BLOCK + t;
    const int e1 = e0 + 256;
    const bool v0 = (e0 < N_EDGES);
    const bool v1 = (e1 < N_EDGES);
    const int ec0 = v0 ? e0 : 0;
    const int ec1 = v1 ? e1 : 0;

    // ---- index loads (both edges) ----
    int s0 = src[ec0], d0 = dst[ec0], r0 = rel[ec0];
    int s1i = src[ec1], d1i = dst[ec1], r1 = rel[ec1];

    // ---- score-dot gathers + he rows (independent) ----
    float2 ss0 = s13[s0], sd0 = s13[d0];
    float2 ss1 = s13[s1i], sd1 = s13[d1i];

    const float4* q0 = (const float4*)(he + (size_t)ec0 * IN_DIM);
    const float4* q1 = (const float4*)(he + (size_t)ec1 * IN_DIM);
    float4 he00 = q0[0], he01 = q0[1], he02 = q0[2], he03 = q0[3];
    float4 he10 = q1[0], he11 = q1[1], he12 = q1[2], he13 = q1[3];

    // ---- h[src] rows ----
    const float4* p0 = (const float4*)(h + (size_t)s0 * IN_DIM);
    const float4* p1 = (const float4*)(h + (size_t)s1i * IN_DIM);
    float4 a0 = p0[0], a1 = p0[1], a2 = p0[2], a3 = p0[3];
    float4 b0 = p1[0], b1 = p1[1], b2 = p1[2], b3 = p1[3];

    // ---- claim list slots early (latency overlapped with matvec) ----
    int old0 = 0, old1 = 0;
    if (v0) old0 = atomicExch(&head[d0], e0);
    if (v1) old1 = atomicExch(&head[d1i], e1);

    // ---- scores ----
    float sc0 = ss0.x + sd0.y;
    float sc1 = ss1.x + sd1.y;
    {
        float t0 = he00.x*avec[16] + he00.y*avec[17] + he00.z*avec[18] + he00.w*avec[19]
                 + he01.x*avec[20] + he01.y*avec[21] + he01.z*avec[22] + he01.w*avec[23]
                 + he02.x*avec[24] + he02.y*avec[25] + he02.z*avec[26] + he02.w*avec[27]
                 + he03.x*avec[28] + he03.y*avec[29] + he03.z*avec[30] + he03.w*avec[31];
        float t1 = he10.x*avec[16] + he10.y*avec[17] + he10.z*avec[18] + he10.w*avec[19]
                 + he11.x*avec[20] + he11.y*avec[21] + he11.z*avec[22] + he11.w*avec[23]
                 + he12.x*avec[24] + he12.y*avec[25] + he12.z*avec[26] + he12.w*avec[27]
                 + he13.x*avec[28] + he13.y*avec[29] + he13.z*avec[30] + he13.w*avec[31];
        sc0 += t0;
        sc1 += t1;
    }

    float hs0[IN_DIM] = {a0.x,a0.y,a0.z,a0.w, a1.x,a1.y,a1.z,a1.w,
                         a2.x,a2.y,a2.z,a2.w, a3.x,a3.y,a3.z,a3.w};
    float hs1[IN_DIM] = {b0.x,b0.y,b0.z,b0.w, b1.x,b1.y,b1.z,b1.w,
                         b2.x,b2.y,b2.z,b2.w, b3.x,b3.y,b3.z,b3.w};

    // ---- two independent 16x16 matvecs, interleaved for MLP ----
    const float4* W0 = (const float4*)(Wrel + (size_t)r0 * 256);
    const float4* W1 = (const float4*)(Wrel + (size_t)r1 * 256);
    float4 c00 = {0,0,0,0}, c01 = {0,0,0,0}, c02 = {0,0,0,0}, c03 = {0,0,0,0};
    float4 c10 = {0,0,0,0}, c11 = {0,0,0,0}, c12 = {0,0,0,0}, c13 = {0,0,0,0};
    #pragma unroll
    for (int i = 0; i < IN_DIM; ++i) {
        float4 w00 = W0[i*4+0], w01 = W0[i*4+1], w02 = W0[i*4+2], w03 = W0[i*4+3];
        float4 w10 = W1[i*4+0], w11 = W1[i*4+1], w12 = W1[i*4+2], w13 = W1[i*4+3];
        float u = hs0[i], w = hs1[i];
        c00.x += u*w00.x; c00.y += u*w00.y; c00.z += u*w00.z; c00.w += u*w00.w;
        c01.x += u*w01.x; c01.y += u*w01.y; c01.z += u*w01.z; c01.w += u*w01.w;
        c02.x += u*w02.x; c02.y += u*w02.y; c02.z += u*w02.z; c02.w += u*w02.w;
        c03.x += u*w03.x; c03.y += u*w03.y; c03.z += u*w03.z; c03.w += u*w03.w;
        c10.x += w*w10.x; c10.y += w*w10.y; c10.z += w*w10.z; c10.w += w*w10.w;
        c11.x += w*w11.x; c11.y += w*w11.y; c11.z += w*w11.z; c11.w += w*w11.w;
        c12.x += w*w12.x; c12.y += w*w12.y; c12.z += w*w12.z; c12.w += w*w12.w;
        c13.x += w*w13.x; c13.y += w*w13.y; c13.z += w*w13.z; c13.w += w*w13.w;
    }

    if (v0) {
        float4* out = (float4*)(msg + (size_t)e0 * OUT_DIM);
        c00.x*=sc0; c00.y*=sc0; c00.z*=sc0; c00.w*=sc0;
        c01.x*=sc0; c01.y*=sc0; c01.z*=sc0; c01.w*=sc0;
        c02.x*=sc0; c02.y*=sc0; c02.z*=sc0; c02.w*=sc0;
        c03.x*=sc0; c03.y*=sc0; c03.z*=sc0; c03.w*=sc0;
        out[0]=c00; out[1]=c01; out[2]=c02; out[3]=c03;
        next[e0] = old0;
    }
    if (v1) {
        float4* out = (float4*)(msg + (size_t)e1 * OUT_DIM);
        c10.x*=sc1; c10.y*=sc1; c10.z*=sc1; c10.w*=sc1;
        c11.x*=sc1; c11.y*=sc1; c11.z*=sc1; c11.w*=sc1;
        c12.x*=sc1; c12.y*=sc1; c12.z*=sc1; c12.w*=sc1;
        c13.x*=sc1; c13.y*=sc1; c13.z*=sc1; c13.w*=sc1;
        out[0]=c10; out[1]=c11; out[2]=c12; out[3]=c13;
        next[e1] = old1;
    }
}

// ---------------------------------------------------------------------------
// Reduce: 16 threads per node walk the dst linked list; coalesced 64B msg
// rows; chase loads broadcast across the 16 lanes. No atomics.
// ---------------------------------------------------------------------------
__global__ __launch_bounds__(256) void reduce_kernel(
    const float* __restrict__ msg,
    const int* __restrict__ head,
    const int* __restrict__ next,
    float* __restrict__ hout)
{
    int tid = blockIdx.x * blockDim.x + threadIdx.x;
    int n = tid >> 4;
    int o = tid & 15;
    if (n >= N_NODES) return;

    float acc = 0.f;
    int e = head[n];
    while (e >= 0) {
        int en = next[e];          // issue chase load
        acc += msg[(size_t)e * OUT_DIM + o];
        e = en;
    }
    hout[(size_t)n * OUT_DIM + o] = acc;
}

// ---------------------------------------------------------------------------
// Fallback (ws too small): direct atomic scatter.
// ---------------------------------------------------------------------------
__global__ __launch_bounds__(256) void edge_atomic_kernel(
    const float* __restrict__ h,
    const float* __restrict__ he,
    const int* __restrict__ src,
    const int* __restrict__ dst,
    const int* __restrict__ rel,
    const float* __restrict__ Wrel,
    const float* __restrict__ avec,
    float* __restrict__ hout)
{
    int e = blockIdx.x * blockDim.x + threadIdx.x;
    if (e >= N_EDGES) return;
    int s = src[e], d = dst[e], r = rel[e];
    float hs[IN_DIM];
    const float4* p = (const float4*)(h + (size_t)s * IN_DIM);
    #pragma unroll
    for (int i = 0; i < 4; ++i) {
        float4 v = p[i];
        hs[4*i+0] = v.x; hs[4*i+1] = v.y; hs[4*i+2] = v.z; hs[4*i+3] = v.w;
    }
    float score = 0.f;
    #pragma unroll
    for (int i = 0; i < IN_DIM; ++i) score += hs[i] * avec[i];
    const float4* q = (const float4*)(he + (size_t)e * IN_DIM);
    #pragma unroll
    for (int i = 0; i < 4; ++i) {
        float4 v = q[i];
        score += v.x * avec[16+4*i] + v.y * avec[17+4*i] + v.z * avec[18+4*i] + v.w * avec[19+4*i];
    }
    const float4* pd = (const float4*)(h + (size_t)d * IN_DIM);
    #pragma unroll
    for (int i = 0; i < 4; ++i) {
        float4 v = pd[i];
        score += v.x * avec[32+4*i] + v.y * avec[33+4*i] + v.z * avec[34+4*i] + v.w * avec[35+4*i];
    }
    float acc[OUT_DIM];
    #pragma unroll
    for (int o = 0; o < OUT_DIM; ++o) acc[o] = 0.f;
    const float* W = Wrel + (size_t)r * 256;
    #pragma unroll
    for (int i = 0; i < IN_DIM; ++i) {
        float hv = hs[i];
        #pragma unroll
        for (int o = 0; o < OUT_DIM; ++o) acc[o] += hv * W[i * OUT_DIM + o];
    }
    float* outp = hout + (size_t)d * OUT_DIM;
    #pragma unroll
    for (int o = 0; o < OUT_DIM; ++o) atomicAdd(outp + o, acc[o] * score);
}

extern "C" void kernel_launch(void* const* d_in, const int* in_sizes, int n_in,
                              void* d_out, int out_size, void* d_ws, size_t ws_size,
                              hipStream_t stream) {
    const float* h      = (const float*)d_in[0];
    const float* he     = (const float*)d_in[1];
    const float* Ws     = (const float*)d_in[2];
    const float* Wa     = (const float*)d_in[3];
    const float* weight = (const float*)d_in[4];
    const float* w_comp = (const float*)d_in[5];
    const int*   src    = (const int*)d_in[6];
    const int*   dst    = (const int*)d_in[7];
    const int*   rel    = (const int*)d_in[8];
    float* hout = (float*)d_out;

    // ws layout (float offsets)
    const size_t OFF_WREL = 0;         // 23040 f
    const size_t OFF_AVEC = 23040;     // 48 f (+16 pad)
    const size_t OFF_S13  = 23104;     // 100000 f (float2[50000])
    const size_t OFF_HEAD = 123104;    // 50000 i
    const size_t OFF_NEXT = 173104;    // 800000 i
    const size_t OFF_MSG  = 973104;    // 12,800,000 f (16-f aligned: 973104 % 16 == 0)
    const size_t NEED_BYTES = (OFF_MSG + (size_t)N_EDGES * OUT_DIM) * 4;

    float* wsf  = (float*)d_ws;
    float* Wrel = wsf + OFF_WREL;
    float* avec = wsf + OFF_AVEC;

    {
        int total = N_RELS * IN_DIM * OUT_DIM + 48;
        prep_kernel<<<(total + 255) / 256, 256, 0, stream>>>(Ws, Wa, weight, w_comp, Wrel, avec);
    }

    if (ws_size >= NEED_BYTES) {
        float2* s13 = (float2*)(wsf + OFF_S13);
        int* headp  = (int*)(wsf + OFF_HEAD);
        int* nextp  = (int*)(wsf + OFF_NEXT);
        float* msg  = wsf + OFF_MSG;

        hipMemsetAsync(headp, 0xFF, N_NODES * sizeof(int), stream);  // head = -1
        node_dots_kernel<<<(N_NODES + 255) / 256, 256, 0, stream>>>(h, avec, s13);
        {
            int blocks = (N_EDGES + EDGES_PER_BLOCK - 1) / EDGES_PER_BLOCK;
            compute_kernel<<<blocks, 256, 0, stream>>>(
                h, he, src, dst, rel, Wrel, avec, s13, headp, nextp, msg);
        }
        reduce_kernel<<<(N_NODES * OUT_DIM + 255) / 256, 256, 0, stream>>>(
            msg, headp, nextp, hout);
    } else {
        hipMemsetAsync(d_out, 0, (size_t)out_size * sizeof(float), stream);
        edge_atomic_kernel<<<(N_EDGES + 255) / 256, 256, 0, stream>>>(
            h, he, src, dst, rel, Wrel, avec, hout);
    }
}

// Round 4
// 238.372 us; speedup vs baseline: 3.2448x; 1.5420x over previous
//
#include <hip/hip_runtime.h>

#define N_NODES 50000
#define N_EDGES 800000
#define IN_DIM 16
#define OUT_DIM 16
#define N_RELS 90
#define N_BASES 30

#define SCAN_BLOCKS 196   // 196*256 = 50176 >= 50000
#define DOTS_BLOCKS 196
#define COUNT_BLOCKS 3125 // 3125*256 = 800000

__device__ __forceinline__ float4 shfl_xor4(float4 v, int m) {
    float4 r;
    r.x = __shfl_xor(v.x, m); r.y = __shfl_xor(v.y, m);
    r.z = __shfl_xor(v.z, m); r.w = __shfl_xor(v.w, m);
    return r;
}

// ---------------------------------------------------------------------------
// Prep: W_rel (basis recombination, reference reshape semantics) + folded
// attention vectors a1,a2,a3 (Ws^T @ Wa chunks).
// ---------------------------------------------------------------------------
__global__ __launch_bounds__(256) void prep_kernel(
    const float* __restrict__ Ws,      // [16,16]  (out,in)
    const float* __restrict__ Wa,      // [1,48]
    const float* __restrict__ weight,  // [30,16,16] flat
    const float* __restrict__ w_comp,  // [90,30]
    float* __restrict__ Wrel,          // [90*256]
    float* __restrict__ avec)          // [48]
{
    int f = blockIdx.x * blockDim.x + threadIdx.x;
    if (f < N_RELS * IN_DIM * OUT_DIM) {
        int a   = f / (N_RELS * OUT_DIM);
        int rem = f % (N_RELS * OUT_DIM);
        int r   = rem / OUT_DIM;
        int o   = rem % OUT_DIM;
        float acc = 0.f;
        #pragma unroll
        for (int b = 0; b < N_BASES; ++b)
            acc += w_comp[r * N_BASES + b] * weight[a * (N_BASES * OUT_DIM) + b * OUT_DIM + o];
        Wrel[f] = acc;
    } else if (f < N_RELS * IN_DIM * OUT_DIM + 48) {
        int g = f - N_RELS * IN_DIM * OUT_DIM;
        int k = g / IN_DIM;
        int i = g % IN_DIM;
        float acc = 0.f;
        #pragma unroll
        for (int o = 0; o < OUT_DIM; ++o)
            acc += Wa[k * OUT_DIM + o] * Ws[o * IN_DIM + i];
        avec[g] = acc;
    }
}

// ---------------------------------------------------------------------------
// Fused: per-node score dots (first DOTS_BLOCKS blocks) + dst histogram.
// ---------------------------------------------------------------------------
__global__ __launch_bounds__(256) void dots_count_kernel(
    const float* __restrict__ h,
    const float* __restrict__ avec,
    float2* __restrict__ s13,
    const int* __restrict__ dst,
    int* __restrict__ cnt)
{
    int b = blockIdx.x;
    if (b < DOTS_BLOCKS) {
        int n = b * 256 + threadIdx.x;
        if (n >= N_NODES) return;
        const float4* p = (const float4*)(h + (size_t)n * IN_DIM);
        float d1 = 0.f, d3 = 0.f;
        #pragma unroll
        for (int i = 0; i < 4; ++i) {
            float4 v = p[i];
            d1 += v.x * avec[4*i+0] + v.y * avec[4*i+1] + v.z * avec[4*i+2] + v.w * avec[4*i+3];
            d3 += v.x * avec[32+4*i+0] + v.y * avec[32+4*i+1] + v.z * avec[32+4*i+2] + v.w * avec[32+4*i+3];
        }
        s13[n] = make_float2(d1, d3);
    } else {
        int e = (b - DOTS_BLOCKS) * 256 + threadIdx.x;
        if (e < N_EDGES) atomicAdd(&cnt[dst[e]], 1);
    }
}

// ---------------------------------------------------------------------------
// 2-level scan: A) per-block sums, B) scan of block sums, C) add-back.
// ---------------------------------------------------------------------------
__global__ __launch_bounds__(256) void scanA_kernel(
    const int* __restrict__ cnt, int* __restrict__ partial)
{
    __shared__ int sm[256];
    int idx = blockIdx.x * 256 + threadIdx.x;
    sm[threadIdx.x] = (idx < N_NODES) ? cnt[idx] : 0;
    __syncthreads();
    #pragma unroll
    for (int st = 128; st > 0; st >>= 1) {
        if (threadIdx.x < st) sm[threadIdx.x] += sm[threadIdx.x + st];
        __syncthreads();
    }
    if (threadIdx.x == 0) partial[blockIdx.x] = sm[0];
}

__global__ __launch_bounds__(256) void scanB_kernel(
    const int* __restrict__ partial, int* __restrict__ pbase, int* __restrict__ base)
{
    __shared__ int sm[256];
    int t = threadIdx.x;
    int v = (t < SCAN_BLOCKS) ? partial[t] : 0;
    sm[t] = v;
    __syncthreads();
    #pragma unroll
    for (int d = 1; d < 256; d <<= 1) {
        int u = (t >= d) ? sm[t - d] : 0;
        __syncthreads();
        sm[t] += u;
        __syncthreads();
    }
    if (t < SCAN_BLOCKS) pbase[t] = sm[t] - v;   // exclusive
    if (t == 0) base[N_NODES] = N_EDGES;
}

__global__ __launch_bounds__(256) void scanC_kernel(
    const int* __restrict__ cnt, const int* __restrict__ pbase,
    int* __restrict__ base, int* __restrict__ cursor)
{
    __shared__ int sm[256];
    int t = threadIdx.x;
    int idx = blockIdx.x * 256 + t;
    int v = (idx < N_NODES) ? cnt[idx] : 0;
    sm[t] = v;
    __syncthreads();
    #pragma unroll
    for (int d = 1; d < 256; d <<= 1) {
        int u = (t >= d) ? sm[t - d] : 0;
        __syncthreads();
        sm[t] += u;
        __syncthreads();
    }
    if (idx < N_NODES) {
        int b = pbase[blockIdx.x] + sm[t] - v;
        base[idx] = b;
        cursor[idx] = b;
    }
}

// ---------------------------------------------------------------------------
// Edge compute: 4 lanes per edge (lane q owns output columns 4q..4q+3).
// Every global load/store instruction is line-dense: 16 groups x 64B.
// ---------------------------------------------------------------------------
__global__ __launch_bounds__(256) void compute_kernel(
    const float* __restrict__ h,
    const float* __restrict__ he,
    const int* __restrict__ src,
    const int* __restrict__ dst,
    const int* __restrict__ rel,
    const float* __restrict__ Wrel,
    const float* __restrict__ avec,
    const float2* __restrict__ s13,
    int* __restrict__ cursor,
    float* __restrict__ msg)   // [N_EDGES*16], permuted by dst-segment
{
    int tid = blockIdx.x * 256 + threadIdx.x;
    int g = tid >> 2;           // edge
    int q = threadIdx.x & 3;    // quarter
    if (g >= N_EDGES) return;

    int s = src[g], d = dst[g], r = rel[g];

    // dense 64B-per-group row reads
    float4 heq = *(const float4*)(he + (size_t)g * IN_DIM + q * 4);
    float4 hq  = *(const float4*)(h  + (size_t)s * IN_DIM + q * 4);
    float2 svs = s13[s];
    float2 svd = s13[d];

    // claim CSR slot early (lane 0 of group), broadcast
    int pos = 0;
    if (q == 0) pos = atomicAdd(&cursor[d], 1);
    pos = __shfl(pos, (threadIdx.x & 63) & ~3);

    // he-dot: per-lane partial + 4-lane butterfly
    float4 av = *(const float4*)(avec + 16 + 4 * q);
    float pd = heq.x * av.x + heq.y * av.y + heq.z * av.z + heq.w * av.w;
    pd += __shfl_xor(pd, 1);
    pd += __shfl_xor(pd, 2);
    float score = svs.x + svd.y + pd;

    // allgather h[src] row across the 4 lanes
    float4 o1 = shfl_xor4(hq, 1);
    float4 o2 = shfl_xor4(hq, 2);
    float4 o3 = shfl_xor4(o1, 2);
    bool q0 = (q == 0), q1 = (q == 1), q2 = (q == 2);
    float4 row0 = q0 ? hq : q1 ? o1 : q2 ? o2 : o3;
    float4 row1 = q0 ? o1 : q1 ? hq : q2 ? o3 : o2;
    float4 row2 = q0 ? o2 : q1 ? o3 : q2 ? hq : o1;
    float4 row3 = q0 ? o3 : q1 ? o2 : q2 ? o1 : hq;
    float hs[16] = {row0.x,row0.y,row0.z,row0.w, row1.x,row1.y,row1.z,row1.w,
                    row2.x,row2.y,row2.z,row2.w, row3.x,row3.y,row3.z,row3.w};

    // matvec: lane accumulates its output quarter over all 16 inputs.
    // W reads: per instruction, each group reads a contiguous 64B line.
    const float4* W4 = (const float4*)(Wrel + (size_t)r * 256) + q;
    float4 acc = {0.f, 0.f, 0.f, 0.f};
    #pragma unroll
    for (int i = 0; i < 16; ++i) {
        float4 w = W4[i * 4];
        float hv = hs[i];
        acc.x += hv * w.x; acc.y += hv * w.y; acc.z += hv * w.z; acc.w += hv * w.w;
    }
    acc.x *= score; acc.y *= score; acc.z *= score; acc.w *= score;

    // dense store: 16 groups x full 64B lines per instruction
    *(float4*)(msg + (size_t)pos * OUT_DIM + q * 4) = acc;
}

// ---------------------------------------------------------------------------
// Reduce: 16 threads per node stream the contiguous CSR segment. No atomics.
// ---------------------------------------------------------------------------
__global__ __launch_bounds__(256) void reduce_kernel(
    const float* __restrict__ msg,
    const int* __restrict__ base,
    float* __restrict__ hout)
{
    int tid = blockIdx.x * 256 + threadIdx.x;
    int n = tid >> 4;
    int o = tid & 15;
    if (n >= N_NODES) return;

    int beg = base[n];
    int end = base[n + 1];
    float acc = 0.f;
    for (int j = beg; j < end; ++j)
        acc += msg[(size_t)j * OUT_DIM + o];
    hout[(size_t)n * OUT_DIM + o] = acc;
}

// ---------------------------------------------------------------------------
// Fallback (ws too small): direct atomic scatter.
// ---------------------------------------------------------------------------
__global__ __launch_bounds__(256) void edge_atomic_kernel(
    const float* __restrict__ h,
    const float* __restrict__ he,
    const int* __restrict__ src,
    const int* __restrict__ dst,
    const int* __restrict__ rel,
    const float* __restrict__ Wrel,
    const float* __restrict__ avec,
    float* __restrict__ hout)
{
    int e = blockIdx.x * blockDim.x + threadIdx.x;
    if (e >= N_EDGES) return;
    int s = src[e], d = dst[e], r = rel[e];
    float hs[IN_DIM];
    const float4* p = (const float4*)(h + (size_t)s * IN_DIM);
    #pragma unroll
    for (int i = 0; i < 4; ++i) {
        float4 v = p[i];
        hs[4*i+0] = v.x; hs[4*i+1] = v.y; hs[4*i+2] = v.z; hs[4*i+3] = v.w;
    }
    float score = 0.f;
    #pragma unroll
    for (int i = 0; i < IN_DIM; ++i) score += hs[i] * avec[i];
    const float4* qe = (const float4*)(he + (size_t)e * IN_DIM);
    #pragma unroll
    for (int i = 0; i < 4; ++i) {
        float4 v = qe[i];
        score += v.x * avec[16+4*i] + v.y * avec[17+4*i] + v.z * avec[18+4*i] + v.w * avec[19+4*i];
    }
    const float4* pd = (const float4*)(h + (size_t)d * IN_DIM);
    #pragma unroll
    for (int i = 0; i < 4; ++i) {
        float4 v = pd[i];
        score += v.x * avec[32+4*i] + v.y * avec[33+4*i] + v.z * avec[34+4*i] + v.w * avec[35+4*i];
    }
    float acc[OUT_DIM];
    #pragma unroll
    for (int o = 0; o < OUT_DIM; ++o) acc[o] = 0.f;
    const float* W = Wrel + (size_t)r * 256;
    #pragma unroll
    for (int i = 0; i < IN_DIM; ++i) {
        float hv = hs[i];
        #pragma unroll
        for (int o = 0; o < OUT_DIM; ++o) acc[o] += hv * W[i * OUT_DIM + o];
    }
    float* outp = hout + (size_t)d * OUT_DIM;
    #pragma unroll
    for (int o = 0; o < OUT_DIM; ++o) atomicAdd(outp + o, acc[o] * score);
}

extern "C" void kernel_launch(void* const* d_in, const int* in_sizes, int n_in,
                              void* d_out, int out_size, void* d_ws, size_t ws_size,
                              hipStream_t stream) {
    const float* h      = (const float*)d_in[0];
    const float* he     = (const float*)d_in[1];
    const float* Ws     = (const float*)d_in[2];
    const float* Wa     = (const float*)d_in[3];
    const float* weight = (const float*)d_in[4];
    const float* w_comp = (const float*)d_in[5];
    const int*   src    = (const int*)d_in[6];
    const int*   dst    = (const int*)d_in[7];
    const int*   rel    = (const int*)d_in[8];
    float* hout = (float*)d_out;

    // ws layout (float offsets)
    const size_t OFF_WREL   = 0;         // 23040 f
    const size_t OFF_AVEC   = 23040;     // 48 f (+16 pad)
    const size_t OFF_S13    = 23104;     // 100000 f (float2[50000])
    const size_t OFF_CNT    = 123104;    // 50000 i
    const size_t OFF_BASE   = 173104;    // 50001 i (+15 pad)
    const size_t OFF_CURSOR = 223120;    // 50000 i
    const size_t OFF_PART   = 273120;    // 256 i
    const size_t OFF_PBASE  = 273376;    // 256 i
    const size_t OFF_MSG    = 273632;    // 12,800,000 f (16-f aligned)
    const size_t NEED_BYTES = (OFF_MSG + (size_t)N_EDGES * OUT_DIM) * 4;

    float* wsf  = (float*)d_ws;
    float* Wrel = wsf + OFF_WREL;
    float* avec = wsf + OFF_AVEC;

    {
        int total = N_RELS * IN_DIM * OUT_DIM + 48;
        prep_kernel<<<(total + 255) / 256, 256, 0, stream>>>(Ws, Wa, weight, w_comp, Wrel, avec);
    }

    if (ws_size >= NEED_BYTES) {
        float2* s13 = (float2*)(wsf + OFF_S13);
        int* cnt    = (int*)(wsf + OFF_CNT);
        int* csbase = (int*)(wsf + OFF_BASE);
        int* cursor = (int*)(wsf + OFF_CURSOR);
        int* part   = (int*)(wsf + OFF_PART);
        int* pbase  = (int*)(wsf + OFF_PBASE);
        float* msg  = wsf + OFF_MSG;

        hipMemsetAsync(cnt, 0, N_NODES * sizeof(int), stream);
        dots_count_kernel<<<DOTS_BLOCKS + COUNT_BLOCKS, 256, 0, stream>>>(h, avec, s13, dst, cnt);
        scanA_kernel<<<SCAN_BLOCKS, 256, 0, stream>>>(cnt, part);
        scanB_kernel<<<1, 256, 0, stream>>>(part, pbase, csbase);
        scanC_kernel<<<SCAN_BLOCKS, 256, 0, stream>>>(cnt, pbase, csbase, cursor);
        compute_kernel<<<(N_EDGES * 4 + 255) / 256, 256, 0, stream>>>(
            h, he, src, dst, rel, Wrel, avec, s13, cursor, msg);
        reduce_kernel<<<(N_NODES * OUT_DIM + 255) / 256, 256, 0, stream>>>(msg, csbase, hout);
    } else {
        hipMemsetAsync(d_out, 0, (size_t)out_size * sizeof(float), stream);
        edge_atomic_kernel<<<(N_EDGES + 255) / 256, 256, 0, stream>>>(
            h, he, src, dst, rel, Wrel, avec, hout);
    }
}